// Round 3
// baseline (148.539 us; speedup 1.0000x reference)
//
#include <hip/hip_runtime.h>
#include <cstdint>
#include <cstddef>

#define WDIM 1600
#define BDIM 4
#define HDIM 900
#define NV4  225   // float4s per column (900/4)
#define NCHV 4     // ceil(225/64)
#define QCAP 96    // max valid radar entries per column (mean ~27, sigma ~5.1)
#define KBIG (4 * HDIM)
#define BW   6     // query batch width

// Phase 1: one wave per (w,b) column.
__global__ __launch_bounds__(256) void radar_place_kernel(
    const float* __restrict__ radar, const float* __restrict__ mde,
    float* __restrict__ colout /* (W*B, H) */, int direct, float* __restrict__ out)
{
    __shared__ __align__(16) float s_col[4][HDIM];
    __shared__ float s_qd[4][QCAP];
    __shared__ int   s_qy[4][QCAP];

    const int wave = threadIdx.x >> 6;
    const int lane = threadIdx.x & 63;
    const int lane4 = lane << 2;
    const int colid = blockIdx.x * 4 + wave;   // grid exactly W*B/4 blocks
    const float4* mde4   = (const float4*)mde   + (long)colid * NV4;
    const float4* radar4 = (const float4*)radar + (long)colid * NV4;

    float* col  = s_col[wave];
    float4* col4 = (float4*)col;
    float* qd   = s_qd[wave];
    int*   qy   = s_qy[wave];

    const unsigned long long below = (1ull << lane) - 1ull;

    // --- Stage A: vector loads, query compaction, col zero-init ---
    float m[16];
    bool hm = false;
    int Q = 0;
#pragma unroll
    for (int c = 0; c < NCHV; ++c) {
        int i4 = c * 64 + lane;
        bool in = (i4 < NV4);
        float4 mv = in ? mde4[i4] : make_float4(0.f, 0.f, 0.f, 0.f);
        m[c * 4 + 0] = (mv.x != 0.f) ? mv.x : 1e30f;
        m[c * 4 + 1] = (mv.y != 0.f) ? mv.y : 1e30f;
        m[c * 4 + 2] = (mv.z != 0.f) ? mv.z : 1e30f;
        m[c * 4 + 3] = (mv.w != 0.f) ? mv.w : 1e30f;
        hm = hm || (mv.x != 0.f) || (mv.y != 0.f) || (mv.z != 0.f) || (mv.w != 0.f);

        if (in) col4[i4] = make_float4(0.f, 0.f, 0.f, 0.f);

        float4 rv = in ? radar4[i4] : make_float4(0.f, 0.f, 0.f, 0.f);
        unsigned long long b0 = __ballot(rv.x != 0.f);
        unsigned long long b1 = __ballot(rv.y != 0.f);
        unsigned long long b2 = __ballot(rv.z != 0.f);
        unsigned long long b3 = __ballot(rv.w != 0.f);
        int pos = Q + __popcll(b0 & below) + __popcll(b1 & below)
                    + __popcll(b2 & below) + __popcll(b3 & below);
        int y0 = i4 * 4;
        if (rv.x != 0.f) { if (pos < QCAP) { qd[pos] = rv.x; qy[pos] = y0;     } pos++; }
        if (rv.y != 0.f) { if (pos < QCAP) { qd[pos] = rv.y; qy[pos] = y0 + 1; } pos++; }
        if (rv.z != 0.f) { if (pos < QCAP) { qd[pos] = rv.z; qy[pos] = y0 + 2; } pos++; }
        if (rv.w != 0.f) { if (pos < QCAP) { qd[pos] = rv.w; qy[pos] = y0 + 3; } pos++; }
        Q += __popcll(b0) + __popcll(b1) + __popcll(b2) + __popcll(b3);
    }
    if (Q > QCAP) Q = QCAP;
    const bool has_mde = (__ballot(hm) != 0ull);

    // occupancy bitmask: bit (c*4+j) of lane l <=> y = (c*64+l)*4+j occupied.
    // pre-set invalid slots (i4 >= NV4 i.e. chunk 3, lane >= 33) as occupied.
    unsigned occ = (lane >= 33) ? 0xF000u : 0u;

    // --- fused argmin + placement, BW queries per batch ---
    for (int t = 0; t < Q; t += BW) {
        float d[BW];
#pragma unroll
        for (int i = 0; i < BW; ++i) {
            int idx = (t + i < Q) ? (t + i) : (Q - 1);
            d[i] = qd[idx];                 // wave-uniform broadcast LDS read
        }
        float bd[BW], bo[BW];
        int bi[BW];
#pragma unroll
        for (int i = 0; i < BW; ++i) { bd[i] = 3.4e38f; bi[i] = 0; }
        // per-lane scan: yy ascending within lane -> strict < keeps first index
#pragma unroll
        for (int c = 0; c < NCHV; ++c) {
#pragma unroll
            for (int j = 0; j < 4; ++j) {
                float mm = m[c * 4 + j];
                int yy = c * 256 + lane4 + j;
#pragma unroll
                for (int i = 0; i < BW; ++i) {
                    float af = fabsf(mm - d[i]);
                    if (af < bd[i]) { bd[i] = af; bi[i] = yy; }
                }
            }
        }
#pragma unroll
        for (int i = 0; i < BW; ++i) bo[i] = bd[i];
        // phase 1: f32 min butterfly (BW interleaved chains)
#pragma unroll
        for (int off = 32; off; off >>= 1)
#pragma unroll
            for (int i = 0; i < BW; ++i)
                bd[i] = fminf(bd[i], __shfl_xor(bd[i], off));
        // phase 2: min index among value-tied lanes == global first index
#pragma unroll
        for (int i = 0; i < BW; ++i)
            bi[i] = (bo[i] == bd[i]) ? bi[i] : 0x7fffffff;
#pragma unroll
        for (int off = 32; off; off >>= 1)
#pragma unroll
            for (int i = 0; i < BW; ++i) {
                int v = __shfl_xor(bi[i], off);
                bi[i] = (v < bi[i]) ? v : bi[i];
            }

        // --- sequential placement (scalar-dominated, no LDS reads) ---
#pragma unroll
        for (int i = 0; i < BW; ++i) {
            if (t + i < Q) {
                int best;
                if (has_mde) best = __builtin_amdgcn_readfirstlane(bi[i]);
                else         best = __builtin_amdgcn_readfirstlane(qy[t + i]);
                float depth = d[i];
                int bi4 = best >> 2, bj = best & 3;
                int bc = bi4 >> 6, bl = bi4 & 63;
                int bbit = bc * 4 + bj;
                unsigned long long bm = __ballot((occ >> bbit) & 1u);
                int final_y = best;
                if ((bm >> bl) & 1ull) {
                    // slow path: key = occ ? KBIG : 2|dy| + (dy<0); argmin
                    int bk = 0x7fffffff, bki = 0;
#pragma unroll
                    for (int c = 0; c < NCHV; ++c) {
#pragma unroll
                        for (int j = 0; j < 4; ++j) {
                            int yy = c * 256 + lane4 + j;
                            int o = (occ >> (c * 4 + j)) & 1u;
                            int dy = yy - best;
                            int ad = dy < 0 ? -dy : dy;
                            int key = o ? KBIG : (2 * ad + (dy < 0 ? 1 : 0));
                            if (key < bk) { bk = key; bki = yy; }
                        }
                    }
                    int bko = bk;
#pragma unroll
                    for (int off = 32; off; off >>= 1) {
                        int v = __shfl_xor(bk, off);
                        bk = (v < bk) ? v : bk;
                    }
                    int c2 = (bko == bk) ? bki : 0x7fffffff;
#pragma unroll
                    for (int off = 32; off; off >>= 1) {
                        int v = __shfl_xor(c2, off);
                        c2 = (v < c2) ? v : c2;
                    }
                    int fk = __builtin_amdgcn_readfirstlane(bk);
                    int gi = __builtin_amdgcn_readfirstlane(c2);
                    final_y = (fk >= KBIG) ? best : gi;
                }
                // mark occupied + write depth
                int fi4 = final_y >> 2, fj = final_y & 3;
                int fc = fi4 >> 6, fl = fi4 & 63;
                if (lane == fl) occ |= (1u << (fc * 4 + fj));
                if (lane == 0) col[final_y] = depth;   // same-wave DS order = RAW safe
            }
        }
    }

    // --- writeout ---
    if (direct) {
        int w_ = colid >> 2, b_ = colid & 3;
#pragma unroll
        for (int c = 0; c < NCHV; ++c) {
            int i4 = c * 64 + lane;
            if (i4 < NV4) {
                float4 v = col4[i4];
                int y = i4 * 4;
                out[((long)(b_ * HDIM + y + 0)) * WDIM + w_] = v.x;
                out[((long)(b_ * HDIM + y + 1)) * WDIM + w_] = v.y;
                out[((long)(b_ * HDIM + y + 2)) * WDIM + w_] = v.z;
                out[((long)(b_ * HDIM + y + 3)) * WDIM + w_] = v.w;
            }
        }
    } else {
        float4* colout4 = (float4*)colout + (long)colid * NV4;
#pragma unroll
        for (int c = 0; c < NCHV; ++c) {
            int i4 = c * 64 + lane;
            if (i4 < NV4) colout4[i4] = col4[i4];
        }
    }
}

// Phase 2: transpose (W*B, H) -> (B, H, W), fully coalesced both sides.
__global__ __launch_bounds__(256) void transpose_kernel(
    const float* __restrict__ colout, float* __restrict__ out)
{
    __shared__ float tile[32][33];
    const int b  = blockIdx.z;
    const int h0 = blockIdx.x * 32;
    const int w0 = blockIdx.y * 32;
    const int tx = threadIdx.x & 31;
    const int ty = threadIdx.x >> 5;  // 0..7
#pragma unroll
    for (int j = 0; j < 4; ++j) {
        int wl = ty + j * 8;
        int w = w0 + wl;
        int h = h0 + tx;
        float v = 0.0f;
        if (h < HDIM && w < WDIM) v = colout[((long)(w * BDIM + b)) * HDIM + h];
        tile[wl][tx] = v;
    }
    __syncthreads();
#pragma unroll
    for (int j = 0; j < 4; ++j) {
        int hl = ty + j * 8;
        int h = h0 + hl;
        int w = w0 + tx;
        if (h < HDIM && w < WDIM)
            out[((long)(b * HDIM + h)) * WDIM + w] = tile[tx][hl];
    }
}

extern "C" void kernel_launch(void* const* d_in, const int* in_sizes, int n_in,
                              void* d_out, int out_size, void* d_ws, size_t ws_size,
                              hipStream_t stream) {
    const float* radar = (const float*)d_in[0];
    const float* mde   = (const float*)d_in[1];
    float* out = (float*)d_out;
    float* ws  = (float*)d_ws;

    const size_t need = (size_t)WDIM * BDIM * HDIM * sizeof(float);
    const int direct = (ws_size < need) ? 1 : 0;

    hipLaunchKernelGGL(radar_place_kernel,
                       dim3(WDIM * BDIM / 4), dim3(256), 0, stream,
                       radar, mde, ws, direct, out);

    if (!direct) {
        dim3 g((HDIM + 31) / 32, WDIM / 32, BDIM);
        hipLaunchKernelGGL(transpose_kernel, g, dim3(256), 0, stream, ws, out);
    }
}